// Round 4
// baseline (189.052 us; speedup 1.0000x reference)
//
#include <hip/hip_runtime.h>
#include <math.h>

#define BATCH 2
#define SEQ   2048
#define HID   1024
#define NHEAD 16
#define HDIM  64
#define MTOT  (BATCH * SEQ)   // 4096
#define QKVN  (3 * HID)       // 3072
#define HBUF  ((size_t)BATCH * NHEAD * SEQ * HDIM)   // elems per q/k/v/vT buf

typedef _Float16 f16x8 __attribute__((ext_vector_type(8)));
typedef _Float16 f16x4 __attribute__((ext_vector_type(4)));
typedef float    f32x4 __attribute__((ext_vector_type(4)));

#define MFMA16(a, b, c) __builtin_amdgcn_mfma_f32_16x16x32_f16((a), (b), (c), 0, 0, 0)

#define GLDS16(gp, lp) __builtin_amdgcn_global_load_lds( \
    (const __attribute__((address_space(1))) void*)(gp), \
    (__attribute__((address_space(3))) void*)(lp), 16, 0, 0)

#if __has_builtin(__builtin_amdgcn_exp2f)
#define EXP2F(x) __builtin_amdgcn_exp2f(x)
#else
#define EXP2F(x) exp2f(x)
#endif

#define SCALE2 0.18033688011f     // 0.125 * log2(e)
#define MASK2  -14426.950408f     // -10000 * log2(e)  -> exp2 == 0 exactly
#define BIAS2  -4.0f              // headroom shift; cancels in normalization

// ---------------------------------------------------------------------------
// Fused prep:
//   blocks [0,2048):    hs fp32 -> fp16 PLAIN row-major [m][1024]
//                       (QKV GEMM swizzle now lives in its staging addresses)
//   blocks [2048,6144): Wqkv fp32 [K][N] -> fp16 PLAIN [N][K];
//                       Wd -> fp16 [N][K] with the OLD 4-chunk swizzle
//                       (dense GEMM unchanged)
// ---------------------------------------------------------------------------
__global__ __launch_bounds__(256) void prep_kernel(
    const float* __restrict__ hs, const float* __restrict__ Wqkv,
    const float* __restrict__ Wd, _Float16* __restrict__ A_h,
    _Float16* __restrict__ outQ, _Float16* __restrict__ outD)
{
    __shared__ _Float16 T[32][36];
    const int gid = blockIdx.x;
    const int tid = threadIdx.x;
    if (gid < 2048) {
        const int ci = gid * 256 + tid;
        const int m = ci >> 7, cc = ci & 127;      // cc = 8-elem chunk 0..127
        const float* src = hs + (size_t)m * 1024 + cc * 8;
        f16x8 o;
#pragma unroll
        for (int j = 0; j < 8; ++j) o[j] = (_Float16)src[j];
        *(f16x8*)(A_h + (size_t)m * 1024 + cc * 8) = o;
        return;
    }
    const int tb = gid - 2048;
    const int bx = tb & 127, k0 = (tb >> 7) * 32;
    const float* in;
    _Float16* out;
    int N, n0;
    bool isQ;
    if (bx < 96) { in = Wqkv; out = outQ; N = QKVN; n0 = bx * 32; isQ = true; }
    else         { in = Wd;   out = outD; N = HID;  n0 = (bx - 96) * 32; isQ = false; }
    {
        const int r = tid >> 3, c4 = (tid & 7) * 4;
        float4 v = *(const float4*)(in + (size_t)(k0 + r) * N + n0 + c4);
        T[r][c4 + 0] = (_Float16)v.x;
        T[r][c4 + 1] = (_Float16)v.y;
        T[r][c4 + 2] = (_Float16)v.z;
        T[r][c4 + 3] = (_Float16)v.w;
    }
    __syncthreads();
    {
        const int nn = tid >> 3, k4 = (tid & 7) * 4;
        const int n = n0 + nn;
        f16x4 o;
        o[0] = T[k4 + 0][nn]; o[1] = T[k4 + 1][nn];
        o[2] = T[k4 + 2][nn]; o[3] = T[k4 + 3][nn];
        if (isQ) {
            *(f16x4*)(out + (size_t)n * 1024 + k0 + k4) = o;   // plain [N][K]
        } else {
            const int pos = ((k4 >> 3) ^ (n & 3)), half = (k4 >> 2) & 1;
            *(f16x4*)(out + (size_t)n * 1024 + k0 + pos * 8 + half * 4) = o;
        }
    }
}

// ---------------------------------------------------------------------------
// QKV GEMM, 256x256 tile, BK=32, 8 waves (2M x 4N), counted-vmcnt pipeline.
// LDS = 4-slot ring x (A 256x32 + B 256x32) = 128 KB. At tile t: issue the 4
// staging loads for tile t+3 (slot (t-1)&3, dead since t-1's barrier), then
// 32 MFMA with quadrant-interleaved ds_reads, then s_waitcnt vmcnt(8) (keeps
// t+2/t+3's 8 loads in flight; t+1's loads are ~2 tiles old -> zero wait),
// barrier, preload next tile's first operands. vmcnt never drains to 0
// except the 2-iteration tail.
// Swizzle: stored chunk = logical ^ ((row>>1)&3) (64B rows, balanced banks),
// applied via per-lane GLOBAL source addresses (LDS dest linear, A_h/WqkvT
// plain). Read side: per-thread constant pc = (q4 ^ ((a>>1)&3))*8.
// Epilogue: q / k(row-swizzled) / vT(transposed+swizzled) scatter, verified.
// ---------------------------------------------------------------------------
__global__ __launch_bounds__(512, 2) void qkv_gemm8(
    const _Float16* __restrict__ A, const _Float16* __restrict__ Bt,
    const float* __restrict__ bias, _Float16* __restrict__ base)
{
    __shared__ _Float16 S[4][2][8192];   // [slot][A|B][256 rows * 32 cols]
    const int tid = threadIdx.x;
    const int w = tid >> 6, l = tid & 63;
    const int a = l & 15, q4 = l >> 4;
    // 192 blocks -> 8 XCD chunks of 24, each a 6(bx) x 4(by) rectangle
    const int xc = blockIdx.x & 7, loc = blockIdx.x >> 3;
    const int bx = (xc & 1) * 6 + loc % 6;
    const int by = (xc >> 1) * 4 + loc / 6;
    const int m0 = by * 256, n0 = bx * 256;
    const int wm = (w >> 2) * 128, wn = (w & 3) * 64;

    // staging source: element for stored chunk (tid&3) of row (tid>>2) is
    // logical chunk (tid&3) ^ ((row>>1)&3) = (tid&3) ^ ((tid>>3)&3)
    const int csw = (((tid & 3) ^ ((tid >> 3) & 3)) << 3);
    const _Float16* gAs = A  + (size_t)(m0 + (tid >> 2)) * 1024 + csw;
    const _Float16* gBs = Bt + (size_t)(n0 + (tid >> 2)) * 1024 + csw;

    auto stage_tile = [&](int kt) {
        const int s = kt & 3;
        const size_t ko = (size_t)kt * 32;
        GLDS16(gAs + ko,          &S[s][0][0] + tid * 8);
        GLDS16(gAs + 131072 + ko, &S[s][0][0] + 4096 + tid * 8);   // +128 rows
        GLDS16(gBs + ko,          &S[s][1][0] + tid * 8);
        GLDS16(gBs + 131072 + ko, &S[s][1][0] + 4096 + tid * 8);
    };

    // prologue: stage tiles 0,1,2; wait tile 0 (keep 8 newest in flight)
    stage_tile(0); stage_tile(1); stage_tile(2);
    asm volatile("s_waitcnt vmcnt(8)" ::: "memory");
    __builtin_amdgcn_sched_barrier(0);
    __builtin_amdgcn_s_barrier();
    __builtin_amdgcn_sched_barrier(0);

    f32x4 acc[8][4];
#pragma unroll
    for (int i = 0; i < 8; ++i)
#pragma unroll
        for (int j = 0; j < 4; ++j) acc[i][j] = (f32x4){0.f, 0.f, 0.f, 0.f};

    const int pc = ((q4 ^ ((a >> 1) & 3)) << 3);
#define FRG(SP, row_) (*(const f16x8*)&(SP)[(row_) * 32 + pc])

    f16x8 af[8], bf[4];
    {   // preload tile-0 first operands
        const _Float16* sA = &S[0][0][0];
        const _Float16* sB = &S[0][1][0];
#pragma unroll
        for (int i = 0; i < 4; ++i) af[i] = FRG(sA, wm + i * 16 + a);
        bf[0] = FRG(sB, wn + a);
        bf[1] = FRG(sB, wn + 16 + a);
    }

#pragma unroll 4
    for (int t = 0; t < 32; ++t) {
        const _Float16* sA = &S[t & 3][0][0];
        const _Float16* sB = &S[t & 3][1][0];
        if (t <= 28) stage_tile(t + 3);

        // Q0: rows wm..+63 x cols wn..+31
        __builtin_amdgcn_s_setprio(1);
#pragma unroll
        for (int i = 0; i < 4; ++i)
#pragma unroll
            for (int j = 0; j < 2; ++j)
                acc[i][j] = MFMA16(af[i], bf[j], acc[i][j]);
        __builtin_amdgcn_s_setprio(0);

        // read B-hi, Q1
        bf[2] = FRG(sB, wn + 32 + a);
        bf[3] = FRG(sB, wn + 48 + a);
        __builtin_amdgcn_s_setprio(1);
#pragma unroll
        for (int i = 0; i < 4; ++i)
#pragma unroll
            for (int j = 0; j < 2; ++j)
                acc[i][j + 2] = MFMA16(af[i], bf[j + 2], acc[i][j + 2]);
        __builtin_amdgcn_s_setprio(0);

        // read A-hi, Q2 + Q3
#pragma unroll
        for (int i = 0; i < 4; ++i) af[i + 4] = FRG(sA, wm + 64 + i * 16 + a);
        __builtin_amdgcn_s_setprio(1);
#pragma unroll
        for (int i = 0; i < 4; ++i)
#pragma unroll
            for (int j = 0; j < 2; ++j)
                acc[i + 4][j + 2] = MFMA16(af[i + 4], bf[j + 2], acc[i + 4][j + 2]);
#pragma unroll
        for (int i = 0; i < 4; ++i)
#pragma unroll
            for (int j = 0; j < 2; ++j)
                acc[i + 4][j] = MFMA16(af[i + 4], bf[j], acc[i + 4][j]);
        __builtin_amdgcn_s_setprio(0);

        if (t < 31) {
            // counted wait: t+1's loads are 2 tile-times old -> ~zero stall
            if (t <= 28)      asm volatile("s_waitcnt vmcnt(8)" ::: "memory");
            else if (t == 29) asm volatile("s_waitcnt vmcnt(4)" ::: "memory");
            else              asm volatile("s_waitcnt vmcnt(0)" ::: "memory");
            __builtin_amdgcn_sched_barrier(0);
            __builtin_amdgcn_s_barrier();
            __builtin_amdgcn_sched_barrier(0);
            const _Float16* nA = &S[(t + 1) & 3][0][0];
            const _Float16* nB = &S[(t + 1) & 3][1][0];
#pragma unroll
            for (int i = 0; i < 4; ++i) af[i] = FRG(nA, wm + i * 16 + a);
            bf[0] = FRG(nB, wn + a);
            bf[1] = FRG(nB, wn + 16 + a);
        }
    }
#undef FRG

    // ---- epilogue: scatter to q (plain) / k (row-swizzled) / vT (fused
    //      transpose, chunk-swizzled) — formats identical to previous round
#pragma unroll
    for (int j = 0; j < 4; ++j) {
        const int n = n0 + wn + 16 * j + a;
        const float bv = bias[n];
        const int tq = n >> 10, h = (n >> 6) & 15, d = n & 63;
#pragma unroll
        for (int i = 0; i < 8; ++i) {
            const int mb = m0 + wm + 16 * i + q4 * 4;
            const int bb = mb >> 11, sb = mb & 2047;
            if (tq == 2) {
                f16x4 ov;
#pragma unroll
                for (int r = 0; r < 4; ++r) ov[r] = (_Float16)(acc[i][j][r] + bv);
                const size_t off =
                    ((size_t)((bb * 16 + h) * 64 + d)) * 2048
                    + (sb & ~63)
                    + ((((sb >> 3) & 7) ^ (d & 7)) << 3) + (sb & 7);
                *(f16x4*)(base + 3 * HBUF + off) = ov;
            } else if (tq == 1) {
#pragma unroll
                for (int r = 0; r < 4; ++r) {
                    const int s = sb + r;
                    const _Float16 val = (_Float16)(acc[i][j][r] + bv);
                    const int dk = ((((d >> 3) ^ (s & 7)) & 7) << 3) | (d & 7);
                    base[HBUF + ((size_t)(bb * 16 + h) * 2048 + s) * 64 + dk] = val;
                }
            } else {
#pragma unroll
                for (int r = 0; r < 4; ++r) {
                    const _Float16 val = (_Float16)(acc[i][j][r] + bv);
                    base[((size_t)(bb * 16 + h) * 2048 + sb + r) * 64 + d] = val;
                }
            }
        }
    }
}

// ---------------------------------------------------------------------------
// MFMA fp16 GEMM, TMx128xBK32, swizzled LDS (conflict-free b128 reads).
// Used only as EPI=1 (dense projection): plain fp32 [M][N] store.
// ---------------------------------------------------------------------------
template<int EPI, int TM>
__global__ __launch_bounds__(256) void mfma_gemm(
    const _Float16* __restrict__ A, const _Float16* __restrict__ Bt,
    const float* __restrict__ bias, void* __restrict__ Cout,
    int M, int N, int K)
{
    __shared__ _Float16 As[TM * 32];
    __shared__ _Float16 Bs[128 * 32];
    constexpr int TI = TM / 32;
    constexpr int AR = TM / 4;

    const int tid = threadIdx.x;
    const int w = tid >> 6, l = tid & 63;
    const int a = l & 15, q4 = l >> 4;
    const int m0 = blockIdx.y * TM, n0 = blockIdx.x * 128;
    const int wm = (w >> 1) * (TM / 2), wn = (w & 1) * 64;

    f32x4 acc[TI][4];
#pragma unroll
    for (int i = 0; i < TI; ++i)
#pragma unroll
        for (int j = 0; j < 4; ++j) acc[i][j] = (f32x4){0.f, 0.f, 0.f, 0.f};

    const _Float16* gA = A + (size_t)(m0 + w * AR + (l >> 2)) * K + (l & 3) * 8;
    const _Float16* gB = Bt + (size_t)(n0 + w * 32 + (l >> 2)) * K + (l & 3) * 8;
    _Float16* sA = As + w * AR * 32;
    _Float16* sB = Bs + w * 1024;

    for (int k0 = 0; k0 < K; k0 += 32) {
#pragma unroll
        for (int u = 0; u < TM / 64; ++u)
            GLDS16(gA + (size_t)u * 16 * K + k0, sA + u * 512);
        GLDS16(gB + k0,          sB);
        GLDS16(gB + 16 * K + k0, sB + 512);
        __syncthreads();

        f16x8 af[TI], bf[4];
        const int pa = (q4 ^ (a & 3)) << 3;
#pragma unroll
        for (int i = 0; i < TI; ++i)
            af[i] = *(const f16x8*)&As[(wm + 16 * i + a) * 32 + pa];
#pragma unroll
        for (int j = 0; j < 4; ++j)
            bf[j] = *(const f16x8*)&Bs[(wn + 16 * j + a) * 32 + pa];
#pragma unroll
        for (int i = 0; i < TI; ++i)
#pragma unroll
            for (int j = 0; j < 4; ++j)
                acc[i][j] = MFMA16(af[i], bf[j], acc[i][j]);
        __syncthreads();
    }

    {
        float* C = (float*)Cout;
#pragma unroll
        for (int j = 0; j < 4; ++j) {
            const int n = n0 + wn + 16 * j + a;
            const float bv = bias[n];
#pragma unroll
            for (int i = 0; i < TI; ++i)
#pragma unroll
                for (int r = 0; r < 4; ++r) {
                    const int m = m0 + wm + 16 * i + q4 * 4 + r;
                    C[(size_t)m * N + n] = acc[i][j][r] + bv;
                }
        }
    }
}

// ---------------------------------------------------------------------------
// Paired-tile flash attention, no-max softmax, 1 barrier/tile. (unchanged)
// ---------------------------------------------------------------------------
__global__ __launch_bounds__(256, 2) void attn_mfma(
    const _Float16* __restrict__ qb, const _Float16* __restrict__ kb,
    const _Float16* __restrict__ vtb, _Float16* __restrict__ ctx)
{
    __shared__ _Float16 Ks[2][64 * 64];
    __shared__ _Float16 VT[2][64 * 64];
    __shared__ _Float16 Ps[4][16 * 64];

    const int bid = blockIdx.x;
    const int jj = bid >> 3;
    const int bhIdx = (bid & 7) * 4 + (jj >> 4);   // 0..31
    const int p = jj & 15;
    const int b = bhIdx >> 4, h = bhIdx & 15;
    const int tid = threadIdx.x;
    const int w = tid >> 6, l = tid & 63;
    const int a = l & 15, q4 = l >> 4, a7 = a & 7;
    const size_t bh  = ((size_t)b * NHEAD + h) * SEQ;
    const size_t bhd = ((size_t)b * NHEAD + h) * 64;

    const int qHi = (31 - p) * 64 + w * 16;
    const int qLo = p * 64 + w * 16;
    const int ntiles = 32 - p;

    f16x8 qfh[2], qfl[2];
    {
        const _Float16* qp = qb + (bh + qHi + a) * 64;
        qfh[0] = *(const f16x8*)(qp + q4 * 8);
        qfh[1] = *(const f16x8*)(qp + 32 + q4 * 8);
        const _Float16* ql = qb + (bh + qLo + a) * 64;
        qfl[0] = *(const f16x8*)(ql + q4 * 8);
        qfl[1] = *(const f16x8*)(ql + 32 + q4 * 8);
    }

    f32x4 Oh[4], Ol[4];
#pragma unroll
    for (int c = 0; c < 4; ++c) {
        Oh[c] = (f32x4){0.f, 0.f, 0.f, 0.f};
        Ol[c] = (f32x4){0.f, 0.f, 0.f, 0.f};
    }
    float lh = 0.f, ll = 0.f;

    const _Float16* kg = kb + (bh + w * 16) * 64 + l * 8;
    const int vrow = w * 16 + (l >> 3);
    const _Float16* vg = vtb + (bhd + vrow) * 2048 + (l & 7) * 8;
    _Float16* pbuf = &Ps[w][0];
    const int p0 = (q4 ^ a7) << 3;

    auto stage = [&](int t, int buf) {
        _Float16* ksl = &Ks[buf][0] + w * 1024 + l * 8;
        const _Float16* kt = kg + (size_t)t * 4096;
        GLDS16(kt,       ksl);
        GLDS16(kt + 512, ksl + 512);
        _Float16* vtl = &VT[buf][0] + vrow * 64 + (l & 7) * 8;
        GLDS16(vg + t * 64,            vtl);
        GLDS16(vg + t * 64 + 8 * 2048, vtl + 512);
    };

    stage(0, 0);

    for (int t = 0; t < ntiles; ++t) {
        __syncthreads();                 // tile t landed; prev-iter LDS reads drained
        if (t + 1 < ntiles) stage(t + 1, (t + 1) & 1);

        const _Float16* ksb  = &Ks[t & 1][0];
        const _Float16* vbuf = &VT[t & 1][0];
        const int kt0 = t * 64;
        const bool doLo = (t <= p);

        f32x4 sh[4], sl[4];
#pragma unroll
        for (int n0 = 0; n0 < 4; ++n0) {
            f16x8 kf0 = *(const f16x8*)&ksb[(n0 * 16 + a) * 64 + p0];
            f16x8 kf1 = *(const f16x8*)&ksb[(n0 * 16 + a) * 64 + (p0 ^ 32)];
            f32x4 c = (f32x4){0.f, 0.f, 0.f, 0.f};
            c = MFMA16(kf0, qfh[0], c);
            c = MFMA16(kf1, qfh[1], c);
            sh[n0] = c;
            if (doLo) {
                f32x4 d = (f32x4){0.f, 0.f, 0.f, 0.f};
                d = MFMA16(kf0, qfl[0], d);
                d = MFMA16(kf1, qfl[1], d);
                sl[n0] = d;
            }
        }

        auto half_step = [&](f32x4 st[4], float& lrun, f32x4* O,
                             const bool maskT, const int qbase) {
            if (maskT) {
#pragma unroll
                for (int n0 = 0; n0 < 4; ++n0)
#pragma unroll
                    for (int r = 0; r < 4; ++r) {
                        const int kgl = kt0 + n0 * 16 + q4 * 4 + r;
                        st[n0][r] = (kgl > qbase + a) ? MASK2
                                                      : fmaf(st[n0][r], SCALE2, BIAS2);
                    }
            } else {
#pragma unroll
                for (int n0 = 0; n0 < 4; ++n0)
#pragma unroll
                    for (int r = 0; r < 4; ++r)
                        st[n0][r] = fmaf(st[n0][r], SCALE2, BIAS2);
            }
            float ls = 0.f;
#pragma unroll
            for (int n0 = 0; n0 < 4; ++n0)
#pragma unroll
                for (int r = 0; r < 4; ++r) {
                    const float pe = EXP2F(st[n0][r]);
                    st[n0][r] = pe;
                    ls += pe;
                }
            lrun += ls;
            // P write: keys 16n0+4q4..+3 consecutive -> one b64 per n0
#pragma unroll
            for (int n0 = 0; n0 < 4; ++n0) {
                f16x4 pk;
#pragma unroll
                for (int r = 0; r < 4; ++r) pk[r] = (_Float16)st[n0][r];
                const int pos = (2 * n0 + (q4 >> 1)) ^ a7;
                *(f16x4*)&pbuf[a * 64 + pos * 8 + ((q4 & 1) << 2)] = pk;
            }
            f16x8 pf0 = *(const f16x8*)&pbuf[a * 64 + p0];
            f16x8 pf1 = *(const f16x8*)&pbuf[a * 64 + (p0 ^ 32)];
#pragma unroll
            for (int c = 0; c < 4; ++c) {
                f16x8 vf0 = *(const f16x8*)&vbuf[(c * 16 + a) * 64 + p0];
                f16x8 vf1 = *(const f16x8*)&vbuf[(c * 16 + a) * 64 + (p0 ^ 32)];
                O[c] = MFMA16(vf0, pf0, O[c]);
                O[c] = MFMA16(vf1, pf1, O[c]);
            }
        };

        half_step(sh, lh, Oh, t == 31 - p, qHi);
        if (doLo) half_step(sl, ll, Ol, t == p, qLo);
    }

    // ---- epilogue: reduce l, normalize, store ctx fp16 with GEMM-A swizzle
    auto finish = [&](float lrun, const f32x4* O, const int qbase) {
        float lt = lrun;
        lt += __shfl_xor(lt, 16);
        lt += __shfl_xor(lt, 32);
        const float inv = 1.0f / lt;
        const size_t row = (size_t)b * SEQ + qbase + a;
#pragma unroll
        for (int c = 0; c < 4; ++c) {
            const int d0 = c * 16 + q4 * 4;
            const int kcol = h * 64 + (d0 & ~31)
                           + ((((d0 >> 3) & 3) ^ (a & 3)) << 3) + (d0 & 7);
            f16x4 ov;
#pragma unroll
            for (int r = 0; r < 4; ++r) ov[r] = (_Float16)(O[c][r] * inv);
            *(f16x4*)(ctx + row * HID + kcol) = ov;
        }
    };
    finish(lh, Oh, qHi);
    finish(ll, Ol, qLo);
}

// ---------------------------------------------------------------------------
// WS: [A_h][WqkvT][WdT][q|k(sw)|v(unused)|vT(sw)][ctx]  (all fp16)
// ---------------------------------------------------------------------------
extern "C" void kernel_launch(void* const* d_in, const int* in_sizes, int n_in,
                              void* d_out, int out_size, void* d_ws, size_t ws_size,
                              hipStream_t stream) {
    const float* hs   = (const float*)d_in[0];
    const float* Wqkv = (const float*)d_in[2];
    const float* bqkv = (const float*)d_in[3];
    const float* Wd   = (const float*)d_in[4];
    const float* bd   = (const float*)d_in[5];

    _Float16* A_h   = (_Float16*)d_ws;
    _Float16* WqkvT = A_h + (size_t)MTOT * HID;
    _Float16* WdT   = WqkvT + (size_t)QKVN * HID;
    _Float16* qbuf  = WdT + (size_t)HID * HID;            // q | k(sw) | (v) | vT(sw)
    _Float16* ctxb  = qbuf + 4 * HBUF;

    prep_kernel<<<6144, 256, 0, stream>>>(hs, Wqkv, Wd, A_h, WqkvT, WdT);

    qkv_gemm8<<<192, 512, 0, stream>>>(A_h, WqkvT, bqkv, qbuf);

    attn_mfma<<<512, 256, 0, stream>>>(
        qbuf, qbuf + HBUF, qbuf + 3 * HBUF, ctxb);

    mfma_gemm<1, 64><<<dim3(HID / 128, MTOT / 64), 256, 0, stream>>>(
        ctxb, WdT, bd, d_out, MTOT, HID, HID);
}

// Round 5
// 187.158 us; speedup vs baseline: 1.0101x; 1.0101x over previous
//
#include <hip/hip_runtime.h>
#include <math.h>

#define BATCH 2
#define SEQ   2048
#define HID   1024
#define NHEAD 16
#define HDIM  64
#define MTOT  (BATCH * SEQ)   // 4096
#define QKVN  (3 * HID)       // 3072
#define HBUF  ((size_t)BATCH * NHEAD * SEQ * HDIM)   // elems per q/k/v/vT buf

typedef _Float16 f16x8 __attribute__((ext_vector_type(8)));
typedef _Float16 f16x4 __attribute__((ext_vector_type(4)));
typedef float    f32x4 __attribute__((ext_vector_type(4)));

#define MFMA16(a, b, c) __builtin_amdgcn_mfma_f32_16x16x32_f16((a), (b), (c), 0, 0, 0)

#define GLDS16(gp, lp) __builtin_amdgcn_global_load_lds( \
    (const __attribute__((address_space(1))) void*)(gp), \
    (__attribute__((address_space(3))) void*)(lp), 16, 0, 0)

#if __has_builtin(__builtin_amdgcn_exp2f)
#define EXP2F(x) __builtin_amdgcn_exp2f(x)
#else
#define EXP2F(x) exp2f(x)
#endif

#define SCALE2 0.18033688011f     // 0.125 * log2(e)
#define MASK2  -14426.950408f     // -10000 * log2(e)  -> exp2 == 0 exactly
#define BIAS2  -4.0f              // headroom shift; cancels in normalization

// ---------------------------------------------------------------------------
// Fused prep:
//   blocks [0,2048):    hs fp32 -> fp16 PLAIN row-major [m][1024]
//                       (QKV GEMM swizzle lives in its staging src addresses)
//   blocks [2048,6144): Wqkv fp32 [K][N] -> fp16 PLAIN [N][K];
//                       Wd -> fp16 [N][K] with the OLD 4-chunk swizzle
// ---------------------------------------------------------------------------
__global__ __launch_bounds__(256) void prep_kernel(
    const float* __restrict__ hs, const float* __restrict__ Wqkv,
    const float* __restrict__ Wd, _Float16* __restrict__ A_h,
    _Float16* __restrict__ outQ, _Float16* __restrict__ outD)
{
    __shared__ _Float16 T[32][36];
    const int gid = blockIdx.x;
    const int tid = threadIdx.x;
    if (gid < 2048) {
        const int ci = gid * 256 + tid;
        const int m = ci >> 7, cc = ci & 127;
        const float* src = hs + (size_t)m * 1024 + cc * 8;
        f16x8 o;
#pragma unroll
        for (int j = 0; j < 8; ++j) o[j] = (_Float16)src[j];
        *(f16x8*)(A_h + (size_t)m * 1024 + cc * 8) = o;
        return;
    }
    const int tb = gid - 2048;
    const int bx = tb & 127, k0 = (tb >> 7) * 32;
    const float* in;
    _Float16* out;
    int N, n0;
    bool isQ;
    if (bx < 96) { in = Wqkv; out = outQ; N = QKVN; n0 = bx * 32; isQ = true; }
    else         { in = Wd;   out = outD; N = HID;  n0 = (bx - 96) * 32; isQ = false; }
    {
        const int r = tid >> 3, c4 = (tid & 7) * 4;
        float4 v = *(const float4*)(in + (size_t)(k0 + r) * N + n0 + c4);
        T[r][c4 + 0] = (_Float16)v.x;
        T[r][c4 + 1] = (_Float16)v.y;
        T[r][c4 + 2] = (_Float16)v.z;
        T[r][c4 + 3] = (_Float16)v.w;
    }
    __syncthreads();
    {
        const int nn = tid >> 3, k4 = (tid & 7) * 4;
        const int n = n0 + nn;
        f16x4 o;
        o[0] = T[k4 + 0][nn]; o[1] = T[k4 + 1][nn];
        o[2] = T[k4 + 2][nn]; o[3] = T[k4 + 3][nn];
        if (isQ) {
            *(f16x4*)(out + (size_t)n * 1024 + k0 + k4) = o;   // plain [N][K]
        } else {
            const int pos = ((k4 >> 3) ^ (n & 3)), half = (k4 >> 2) & 1;
            *(f16x4*)(out + (size_t)n * 1024 + k0 + pos * 8 + half * 4) = o;
        }
    }
}

// ---------------------------------------------------------------------------
// QKV GEMM, 256x256 tile, BK=64, 8 waves (2M x 4N) — m201-template schedule:
// fine per-phase interleave AND counted vmcnt (the measured m218-V0 combo).
// Per K-tile, 4 phases; each: {ds_read quadrant frags; stage ONE granule of
// tile t+2 into the CURRENT slot's just-dead region; s_barrier; lgkmcnt(0)+
// sched_barrier; setprio(1); 16 MFMA; setprio(0); s_barrier}.
// Granule deadness: A-lo read P1 -> staged P2; B-lo read P1 -> staged P2;
// B-hi read P2 -> staged P3; A-hi read P3 -> staged P4. The post-MFMA
// barrier is the write-after-read fence (reads complete at each wave's
// lgkmcnt(0) before it). ONE counted s_waitcnt vmcnt(8) per tile at P4
// (keeps t+2's 8 loads in flight across the barrier; guarantees t+1
// landed). Never drains to 0 until the tail.
// LDS rows permuted so each granule is linear: ldsA_row = (i>>2)*128 +
// (w>>2)*64 + 16(i&3)+a; ldsB_row = (j>>1)*128 + (w&3)*32 + 16(j&1)+a.
// XOR-8 chunk swizzle via per-lane global source addrs (A_h/WqkvT plain).
// Epilogue: q / k(row-swizzled) / vT(transposed+swizzled) scatter, verified.
// ---------------------------------------------------------------------------
__global__ __launch_bounds__(512, 2) void qkv_gemm8(
    const _Float16* __restrict__ A, const _Float16* __restrict__ Bt,
    const float* __restrict__ bias, _Float16* __restrict__ base)
{
    __shared__ _Float16 S[2][2][16384];   // [slot][A|B][256 lds_rows * 64]
    const int tid = threadIdx.x;
    const int w = tid >> 6, l = tid & 63;
    const int a = l & 15, q4 = l >> 4, a7 = a & 7;
    // 192 blocks -> 8 XCD chunks of 24, each a 6(bx) x 4(by) rectangle
    const int xc = blockIdx.x & 7, loc = blockIdx.x >> 3;
    const int bx = (xc & 1) * 6 + loc % 6;
    const int by = (xc >> 1) * 4 + loc / 6;
    const int m0 = by * 256, n0 = bx * 256;
    const int wm = (w >> 2) * 128, wn = (w & 3) * 64;

    // staging: stored chunk (tid&7) at lds_row y=(u*64+(tid>>3)) holds
    // logical chunk (tid&7)^(y&7) -> per-lane swizzled global source
    const int csw = (((tid & 7) ^ ((tid >> 3) & 7)) << 3);
    const _Float16* gA0 = A  + (size_t)(m0 + (tid >> 3)) * 1024 + csw;
    const _Float16* gB0 = Bt + (size_t)(n0 + (tid >> 8) * 64 + ((tid >> 3) & 31)) * 1024 + csw;

    // A granule q (lds_rows [q*128,q*128+128)), load u: src row local =
    // u*128 + q*64 + (tid>>3); dest = q*8192 + u*4096 + tid*8 (linear).
    auto stageA = [&](int q, int kt, int sl) {
#pragma unroll
        for (int u = 0; u < 2; ++u)
            GLDS16(gA0 + (size_t)(u * 128 + q * 64) * 1024 + kt * 64,
                   &S[sl][0][0] + q * 8192 + u * 4096 + tid * 8);
    };
    // B granule q, load u: src row local = u*128 + (tid>>8)*64 + q*32 +
    // ((tid>>3)&31) (base folded into gB0); dest linear likewise.
    auto stageB = [&](int q, int kt, int sl) {
#pragma unroll
        for (int u = 0; u < 2; ++u)
            GLDS16(gB0 + (size_t)(u * 128 + q * 32) * 1024 + kt * 64,
                   &S[sl][1][0] + q * 8192 + u * 4096 + tid * 8);
    };

    // prologue: tiles 0 and 1 fully staged; retire tile 0 only
    stageA(0, 0, 0); stageB(0, 0, 0); stageA(1, 0, 0); stageB(1, 0, 0);
    stageA(0, 1, 1); stageB(0, 1, 1); stageA(1, 1, 1); stageB(1, 1, 1);
    asm volatile("s_waitcnt vmcnt(8)" ::: "memory");
    __builtin_amdgcn_sched_barrier(0);
    __builtin_amdgcn_s_barrier();
    __builtin_amdgcn_sched_barrier(0);

    f32x4 acc[8][4];
#pragma unroll
    for (int i = 0; i < 8; ++i)
#pragma unroll
        for (int j = 0; j < 4; ++j) acc[i][j] = (f32x4){0.f, 0.f, 0.f, 0.f};

    // fragment reads through the lds-row permutation + XOR-8 chunk swizzle
#define FA(SP, i_, ks_) (*(const f16x8*)&(SP)[ \
    ((((i_) >> 2) * 128 + (w >> 2) * 64 + ((i_) & 3) * 16 + a) * 64) \
    + ((((ks_) * 4 + q4) ^ a7) << 3)])
#define FB(SP, j_, ks_) (*(const f16x8*)&(SP)[ \
    ((((j_) >> 1) * 128 + (w & 3) * 32 + ((j_) & 1) * 16 + a) * 64) \
    + ((((ks_) * 4 + q4) ^ a7) << 3)])
#define BAR()  __builtin_amdgcn_sched_barrier(0); __builtin_amdgcn_s_barrier(); \
               __builtin_amdgcn_sched_barrier(0)
#define LGKM0() asm volatile("s_waitcnt lgkmcnt(0)" ::: "memory"); \
               __builtin_amdgcn_sched_barrier(0)

#pragma unroll 2
    for (int t = 0; t < 16; ++t) {
        const int sl = t & 1;
        const _Float16* sA = &S[sl][0][0];
        const _Float16* sB = &S[sl][1][0];
        const bool st = (t < 14);

        f16x8 aL[4][2], aH[4][2], bL[2][2], bH[2][2];

        // ---- P1: read aL(8) + bL(4); MFMA Q0
#pragma unroll
        for (int i = 0; i < 4; ++i) {
            aL[i][0] = FA(sA, i, 0); aL[i][1] = FA(sA, i, 1);
        }
#pragma unroll
        for (int j = 0; j < 2; ++j) {
            bL[j][0] = FB(sB, j, 0); bL[j][1] = FB(sB, j, 1);
        }
        asm volatile("s_waitcnt lgkmcnt(8)" ::: "memory");
        BAR();
        LGKM0();
        __builtin_amdgcn_s_setprio(1);
#pragma unroll
        for (int i = 0; i < 4; ++i)
#pragma unroll
            for (int j = 0; j < 2; ++j) {
                acc[i][j] = MFMA16(aL[i][0], bL[j][0], acc[i][j]);
                acc[i][j] = MFMA16(aL[i][1], bL[j][1], acc[i][j]);
            }
        __builtin_amdgcn_s_setprio(0);
        BAR();

        // ---- P2: read bH(4); stage A0+B0 of t+2 (regions dead since P1);
        //          MFMA Q1
#pragma unroll
        for (int j = 0; j < 2; ++j) {
            bH[j][0] = FB(sB, j + 2, 0); bH[j][1] = FB(sB, j + 2, 1);
        }
        if (st) { stageA(0, t + 2, sl); stageB(0, t + 2, sl); }
        BAR();
        LGKM0();
        __builtin_amdgcn_s_setprio(1);
#pragma unroll
        for (int i = 0; i < 4; ++i)
#pragma unroll
            for (int j = 0; j < 2; ++j) {
                acc[i][j + 2] = MFMA16(aL[i][0], bH[j][0], acc[i][j + 2]);
                acc[i][j + 2] = MFMA16(aL[i][1], bH[j][1], acc[i][j + 2]);
            }
        __builtin_amdgcn_s_setprio(0);
        BAR();

        // ---- P3: read aH(8); stage B1 of t+2 (dead since P2); MFMA Q2
#pragma unroll
        for (int i = 0; i < 4; ++i) {
            aH[i][0] = FA(sA, i + 4, 0); aH[i][1] = FA(sA, i + 4, 1);
        }
        if (st) stageB(1, t + 2, sl);
        BAR();
        LGKM0();
        __builtin_amdgcn_s_setprio(1);
#pragma unroll
        for (int i = 0; i < 4; ++i)
#pragma unroll
            for (int j = 0; j < 2; ++j) {
                acc[i + 4][j + 2] = MFMA16(aH[i][0], bH[j][0], acc[i + 4][j + 2]);
                acc[i + 4][j + 2] = MFMA16(aH[i][1], bH[j][1], acc[i + 4][j + 2]);
            }
        __builtin_amdgcn_s_setprio(0);
        BAR();

        // ---- P4: stage A1 of t+2 (dead since P3); MFMA Q3 (reg-only);
        //          counted vmcnt — never 0 until the tail
        if (st) stageA(1, t + 2, sl);
        __builtin_amdgcn_s_setprio(1);
#pragma unroll
        for (int i = 0; i < 4; ++i)
#pragma unroll
            for (int j = 0; j < 2; ++j) {
                acc[i + 4][j] = MFMA16(aH[i][0], bL[j][0], acc[i + 4][j]);
                acc[i + 4][j] = MFMA16(aH[i][1], bL[j][1], acc[i + 4][j]);
            }
        __builtin_amdgcn_s_setprio(0);
        if (st)            asm volatile("s_waitcnt vmcnt(8)" ::: "memory");
        else if (t == 14)  asm volatile("s_waitcnt vmcnt(0)" ::: "memory");
        BAR();
    }
#undef FA
#undef FB
#undef BAR
#undef LGKM0

    // ---- epilogue: scatter to q (plain) / k (row-swizzled) / vT (fused
    //      transpose, chunk-swizzled) — formats identical to previous round
#pragma unroll
    for (int j = 0; j < 4; ++j) {
        const int n = n0 + wn + 16 * j + a;
        const float bv = bias[n];
        const int tq = n >> 10, h = (n >> 6) & 15, d = n & 63;
#pragma unroll
        for (int i = 0; i < 8; ++i) {
            const int mb = m0 + wm + 16 * i + q4 * 4;
            const int bb = mb >> 11, sb = mb & 2047;
            if (tq == 2) {
                f16x4 ov;
#pragma unroll
                for (int r = 0; r < 4; ++r) ov[r] = (_Float16)(acc[i][j][r] + bv);
                const size_t off =
                    ((size_t)((bb * 16 + h) * 64 + d)) * 2048
                    + (sb & ~63)
                    + ((((sb >> 3) & 7) ^ (d & 7)) << 3) + (sb & 7);
                *(f16x4*)(base + 3 * HBUF + off) = ov;
            } else if (tq == 1) {
#pragma unroll
                for (int r = 0; r < 4; ++r) {
                    const int s = sb + r;
                    const _Float16 val = (_Float16)(acc[i][j][r] + bv);
                    const int dk = ((((d >> 3) ^ (s & 7)) & 7) << 3) | (d & 7);
                    base[HBUF + ((size_t)(bb * 16 + h) * 2048 + s) * 64 + dk] = val;
                }
            } else {
#pragma unroll
                for (int r = 0; r < 4; ++r) {
                    const _Float16 val = (_Float16)(acc[i][j][r] + bv);
                    base[((size_t)(bb * 16 + h) * 2048 + sb + r) * 64 + d] = val;
                }
            }
        }
    }
}

// ---------------------------------------------------------------------------
// MFMA fp16 GEMM, TMx128xBK32, swizzled LDS (conflict-free b128 reads).
// Used only as EPI=1 (dense projection): plain fp32 [M][N] store.
// ---------------------------------------------------------------------------
template<int EPI, int TM>
__global__ __launch_bounds__(256) void mfma_gemm(
    const _Float16* __restrict__ A, const _Float16* __restrict__ Bt,
    const float* __restrict__ bias, void* __restrict__ Cout,
    int M, int N, int K)
{
    __shared__ _Float16 As[TM * 32];
    __shared__ _Float16 Bs[128 * 32];
    constexpr int TI = TM / 32;
    constexpr int AR = TM / 4;

    const int tid = threadIdx.x;
    const int w = tid >> 6, l = tid & 63;
    const int a = l & 15, q4 = l >> 4;
    const int m0 = blockIdx.y * TM, n0 = blockIdx.x * 128;
    const int wm = (w >> 1) * (TM / 2), wn = (w & 1) * 64;

    f32x4 acc[TI][4];
#pragma unroll
    for (int i = 0; i < TI; ++i)
#pragma unroll
        for (int j = 0; j < 4; ++j) acc[i][j] = (f32x4){0.f, 0.f, 0.f, 0.f};

    const _Float16* gA = A + (size_t)(m0 + w * AR + (l >> 2)) * K + (l & 3) * 8;
    const _Float16* gB = Bt + (size_t)(n0 + w * 32 + (l >> 2)) * K + (l & 3) * 8;
    _Float16* sA = As + w * AR * 32;
    _Float16* sB = Bs + w * 1024;

    for (int k0 = 0; k0 < K; k0 += 32) {
#pragma unroll
        for (int u = 0; u < TM / 64; ++u)
            GLDS16(gA + (size_t)u * 16 * K + k0, sA + u * 512);
        GLDS16(gB + k0,          sB);
        GLDS16(gB + 16 * K + k0, sB + 512);
        __syncthreads();

        f16x8 af[TI], bf[4];
        const int pa = (q4 ^ (a & 3)) << 3;
#pragma unroll
        for (int i = 0; i < TI; ++i)
            af[i] = *(const f16x8*)&As[(wm + 16 * i + a) * 32 + pa];
#pragma unroll
        for (int j = 0; j < 4; ++j)
            bf[j] = *(const f16x8*)&Bs[(wn + 16 * j + a) * 32 + pa];
#pragma unroll
        for (int i = 0; i < TI; ++i)
#pragma unroll
            for (int j = 0; j < 4; ++j)
                acc[i][j] = MFMA16(af[i], bf[j], acc[i][j]);
        __syncthreads();
    }

    {
        float* C = (float*)Cout;
#pragma unroll
        for (int j = 0; j < 4; ++j) {
            const int n = n0 + wn + 16 * j + a;
            const float bv = bias[n];
#pragma unroll
            for (int i = 0; i < TI; ++i)
#pragma unroll
                for (int r = 0; r < 4; ++r) {
                    const int m = m0 + wm + 16 * i + q4 * 4 + r;
                    C[(size_t)m * N + n] = acc[i][j][r] + bv;
                }
        }
    }
}

// ---------------------------------------------------------------------------
// Paired-tile flash attention, no-max softmax, 1 barrier/tile. (unchanged)
// ---------------------------------------------------------------------------
__global__ __launch_bounds__(256, 2) void attn_mfma(
    const _Float16* __restrict__ qb, const _Float16* __restrict__ kb,
    const _Float16* __restrict__ vtb, _Float16* __restrict__ ctx)
{
    __shared__ _Float16 Ks[2][64 * 64];
    __shared__ _Float16 VT[2][64 * 64];
    __shared__ _Float16 Ps[4][16 * 64];

    const int bid = blockIdx.x;
    const int jj = bid >> 3;
    const int bhIdx = (bid & 7) * 4 + (jj >> 4);   // 0..31
    const int p = jj & 15;
    const int b = bhIdx >> 4, h = bhIdx & 15;
    const int tid = threadIdx.x;
    const int w = tid >> 6, l = tid & 63;
    const int a = l & 15, q4 = l >> 4, a7 = a & 7;
    const size_t bh  = ((size_t)b * NHEAD + h) * SEQ;
    const size_t bhd = ((size_t)b * NHEAD + h) * 64;

    const int qHi = (31 - p) * 64 + w * 16;
    const int qLo = p * 64 + w * 16;
    const int ntiles = 32 - p;

    f16x8 qfh[2], qfl[2];
    {
        const _Float16* qp = qb + (bh + qHi + a) * 64;
        qfh[0] = *(const f16x8*)(qp + q4 * 8);
        qfh[1] = *(const f16x8*)(qp + 32 + q4 * 8);
        const _Float16* ql = qb + (bh + qLo + a) * 64;
        qfl[0] = *(const f16x8*)(ql + q4 * 8);
        qfl[1] = *(const f16x8*)(ql + 32 + q4 * 8);
    }

    f32x4 Oh[4], Ol[4];
#pragma unroll
    for (int c = 0; c < 4; ++c) {
        Oh[c] = (f32x4){0.f, 0.f, 0.f, 0.f};
        Ol[c] = (f32x4){0.f, 0.f, 0.f, 0.f};
    }
    float lh = 0.f, ll = 0.f;

    const _Float16* kg = kb + (bh + w * 16) * 64 + l * 8;
    const int vrow = w * 16 + (l >> 3);
    const _Float16* vg = vtb + (bhd + vrow) * 2048 + (l & 7) * 8;
    _Float16* pbuf = &Ps[w][0];
    const int p0 = (q4 ^ a7) << 3;

    auto stage = [&](int t, int buf) {
        _Float16* ksl = &Ks[buf][0] + w * 1024 + l * 8;
        const _Float16* kt = kg + (size_t)t * 4096;
        GLDS16(kt,       ksl);
        GLDS16(kt + 512, ksl + 512);
        _Float16* vtl = &VT[buf][0] + vrow * 64 + (l & 7) * 8;
        GLDS16(vg + t * 64,            vtl);
        GLDS16(vg + t * 64 + 8 * 2048, vtl + 512);
    };

    stage(0, 0);

    for (int t = 0; t < ntiles; ++t) {
        __syncthreads();                 // tile t landed; prev-iter LDS reads drained
        if (t + 1 < ntiles) stage(t + 1, (t + 1) & 1);

        const _Float16* ksb  = &Ks[t & 1][0];
        const _Float16* vbuf = &VT[t & 1][0];
        const int kt0 = t * 64;
        const bool doLo = (t <= p);

        f32x4 sh[4], sl[4];
#pragma unroll
        for (int n0 = 0; n0 < 4; ++n0) {
            f16x8 kf0 = *(const f16x8*)&ksb[(n0 * 16 + a) * 64 + p0];
            f16x8 kf1 = *(const f16x8*)&ksb[(n0 * 16 + a) * 64 + (p0 ^ 32)];
            f32x4 c = (f32x4){0.f, 0.f, 0.f, 0.f};
            c = MFMA16(kf0, qfh[0], c);
            c = MFMA16(kf1, qfh[1], c);
            sh[n0] = c;
            if (doLo) {
                f32x4 d = (f32x4){0.f, 0.f, 0.f, 0.f};
                d = MFMA16(kf0, qfl[0], d);
                d = MFMA16(kf1, qfl[1], d);
                sl[n0] = d;
            }
        }

        auto half_step = [&](f32x4 st[4], float& lrun, f32x4* O,
                             const bool maskT, const int qbase) {
            if (maskT) {
#pragma unroll
                for (int n0 = 0; n0 < 4; ++n0)
#pragma unroll
                    for (int r = 0; r < 4; ++r) {
                        const int kgl = kt0 + n0 * 16 + q4 * 4 + r;
                        st[n0][r] = (kgl > qbase + a) ? MASK2
                                                      : fmaf(st[n0][r], SCALE2, BIAS2);
                    }
            } else {
#pragma unroll
                for (int n0 = 0; n0 < 4; ++n0)
#pragma unroll
                    for (int r = 0; r < 4; ++r)
                        st[n0][r] = fmaf(st[n0][r], SCALE2, BIAS2);
            }
            float ls = 0.f;
#pragma unroll
            for (int n0 = 0; n0 < 4; ++n0)
#pragma unroll
                for (int r = 0; r < 4; ++r) {
                    const float pe = EXP2F(st[n0][r]);
                    st[n0][r] = pe;
                    ls += pe;
                }
            lrun += ls;
            // P write: keys 16n0+4q4..+3 consecutive -> one b64 per n0
#pragma unroll
            for (int n0 = 0; n0 < 4; ++n0) {
                f16x4 pk;
#pragma unroll
                for (int r = 0; r < 4; ++r) pk[r] = (_Float16)st[n0][r];
                const int pos = (2 * n0 + (q4 >> 1)) ^ a7;
                *(f16x4*)&pbuf[a * 64 + pos * 8 + ((q4 & 1) << 2)] = pk;
            }
            f16x8 pf0 = *(const f16x8*)&pbuf[a * 64 + p0];
            f16x8 pf1 = *(const f16x8*)&pbuf[a * 64 + (p0 ^ 32)];
#pragma unroll
            for (int c = 0; c < 4; ++c) {
                f16x8 vf0 = *(const f16x8*)&vbuf[(c * 16 + a) * 64 + p0];
                f16x8 vf1 = *(const f16x8*)&vbuf[(c * 16 + a) * 64 + (p0 ^ 32)];
                O[c] = MFMA16(vf0, pf0, O[c]);
                O[c] = MFMA16(vf1, pf1, O[c]);
            }
        };

        half_step(sh, lh, Oh, t == 31 - p, qHi);
        if (doLo) half_step(sl, ll, Ol, t == p, qLo);
    }

    // ---- epilogue: reduce l, normalize, store ctx fp16 with GEMM-A swizzle
    auto finish = [&](float lrun, const f32x4* O, const int qbase) {
        float lt = lrun;
        lt += __shfl_xor(lt, 16);
        lt += __shfl_xor(lt, 32);
        const float inv = 1.0f / lt;
        const size_t row = (size_t)b * SEQ + qbase + a;
#pragma unroll
        for (int c = 0; c < 4; ++c) {
            const int d0 = c * 16 + q4 * 4;
            const int kcol = h * 64 + (d0 & ~31)
                           + ((((d0 >> 3) & 3) ^ (a & 3)) << 3) + (d0 & 7);
            f16x4 ov;
#pragma unroll
            for (int r = 0; r < 4; ++r) ov[r] = (_Float16)(O[c][r] * inv);
            *(f16x4*)(ctx + row * HID + kcol) = ov;
        }
    };
    finish(lh, Oh, qHi);
    finish(ll, Ol, qLo);
}

// ---------------------------------------------------------------------------
// WS: [A_h][WqkvT][WdT][q|k(sw)|v(unused)|vT(sw)][ctx]  (all fp16)
// ---------------------------------------------------------------------------
extern "C" void kernel_launch(void* const* d_in, const int* in_sizes, int n_in,
                              void* d_out, int out_size, void* d_ws, size_t ws_size,
                              hipStream_t stream) {
    const float* hs   = (const float*)d_in[0];
    const float* Wqkv = (const float*)d_in[2];
    const float* bqkv = (const float*)d_in[3];
    const float* Wd   = (const float*)d_in[4];
    const float* bd   = (const float*)d_in[5];

    _Float16* A_h   = (_Float16*)d_ws;
    _Float16* WqkvT = A_h + (size_t)MTOT * HID;
    _Float16* WdT   = WqkvT + (size_t)QKVN * HID;
    _Float16* qbuf  = WdT + (size_t)HID * HID;            // q | k(sw) | (v) | vT(sw)
    _Float16* ctxb  = qbuf + 4 * HBUF;

    prep_kernel<<<6144, 256, 0, stream>>>(hs, Wqkv, Wd, A_h, WqkvT, WdT);

    qkv_gemm8<<<192, 512, 0, stream>>>(A_h, WqkvT, bqkv, qbuf);

    attn_mfma<<<512, 256, 0, stream>>>(
        qbuf, qbuf + HBUF, qbuf + 3 * HBUF, ctxb);

    mfma_gemm<1, 64><<<dim3(HID / 128, MTOT / 64), 256, 0, stream>>>(
        ctxb, WdT, bd, d_out, MTOT, HID, HID);
}

// Round 6
// 185.366 us; speedup vs baseline: 1.0199x; 1.0097x over previous
//
#include <hip/hip_runtime.h>
#include <math.h>

#define BATCH 2
#define SEQ   2048
#define HID   1024
#define NHEAD 16
#define HDIM  64
#define MTOT  (BATCH * SEQ)   // 4096
#define QKVN  (3 * HID)       // 3072
#define HBUF  ((size_t)BATCH * NHEAD * SEQ * HDIM)   // elems per q/k/v/vT buf

typedef _Float16 f16x8 __attribute__((ext_vector_type(8)));
typedef _Float16 f16x4 __attribute__((ext_vector_type(4)));
typedef float    f32x4 __attribute__((ext_vector_type(4)));

#define MFMA16(a, b, c) __builtin_amdgcn_mfma_f32_16x16x32_f16((a), (b), (c), 0, 0, 0)

#define GLDS16(gp, lp) __builtin_amdgcn_global_load_lds( \
    (const __attribute__((address_space(1))) void*)(gp), \
    (__attribute__((address_space(3))) void*)(lp), 16, 0, 0)

#if __has_builtin(__builtin_amdgcn_exp2f)
#define EXP2F(x) __builtin_amdgcn_exp2f(x)
#else
#define EXP2F(x) exp2f(x)
#endif

#define SCALE2 0.18033688011f     // 0.125 * log2(e)
#define MASK2  -14426.950408f     // -10000 * log2(e)  -> exp2 == 0 exactly
#define BIAS2  -4.0f              // headroom shift; cancels in normalization

// ---------------------------------------------------------------------------
// Fused prep:
//   blocks [0,2048):    hs fp32 -> fp16 PLAIN row-major [m][1024]
//   blocks [2048,6144): Wqkv fp32 [K][N] -> fp16 PLAIN [N][K];
//                       Wd -> fp16 [N][K] with the OLD 4-chunk swizzle
// ---------------------------------------------------------------------------
__global__ __launch_bounds__(256) void prep_kernel(
    const float* __restrict__ hs, const float* __restrict__ Wqkv,
    const float* __restrict__ Wd, _Float16* __restrict__ A_h,
    _Float16* __restrict__ outQ, _Float16* __restrict__ outD)
{
    __shared__ _Float16 T[32][36];
    const int gid = blockIdx.x;
    const int tid = threadIdx.x;
    if (gid < 2048) {
        const int ci = gid * 256 + tid;
        const int m = ci >> 7, cc = ci & 127;
        const float* src = hs + (size_t)m * 1024 + cc * 8;
        f16x8 o;
#pragma unroll
        for (int j = 0; j < 8; ++j) o[j] = (_Float16)src[j];
        *(f16x8*)(A_h + (size_t)m * 1024 + cc * 8) = o;
        return;
    }
    const int tb = gid - 2048;
    const int bx = tb & 127, k0 = (tb >> 7) * 32;
    const float* in;
    _Float16* out;
    int N, n0;
    bool isQ;
    if (bx < 96) { in = Wqkv; out = outQ; N = QKVN; n0 = bx * 32; isQ = true; }
    else         { in = Wd;   out = outD; N = HID;  n0 = (bx - 96) * 32; isQ = false; }
    {
        const int r = tid >> 3, c4 = (tid & 7) * 4;
        float4 v = *(const float4*)(in + (size_t)(k0 + r) * N + n0 + c4);
        T[r][c4 + 0] = (_Float16)v.x;
        T[r][c4 + 1] = (_Float16)v.y;
        T[r][c4 + 2] = (_Float16)v.z;
        T[r][c4 + 3] = (_Float16)v.w;
    }
    __syncthreads();
    {
        const int nn = tid >> 3, k4 = (tid & 7) * 4;
        const int n = n0 + nn;
        f16x4 o;
        o[0] = T[k4 + 0][nn]; o[1] = T[k4 + 1][nn];
        o[2] = T[k4 + 2][nn]; o[3] = T[k4 + 3][nn];
        if (isQ) {
            *(f16x4*)(out + (size_t)n * 1024 + k0 + k4) = o;   // plain [N][K]
        } else {
            const int pos = ((k4 >> 3) ^ (n & 3)), half = (k4 >> 2) & 1;
            *(f16x4*)(out + (size_t)n * 1024 + k0 + pos * 8 + half * 4) = o;
        }
    }
}

// ---------------------------------------------------------------------------
// QKV GEMM, 256x192 tile -> grid 16x16 = 256 blocks = 1 per CU (FULL machine;
// the 256x256 variant left 64 CUs idle). Round-3 loop structure (best
// measured): stage whole tile t+1 at top of t, quadrant-interleaved ds_reads
// under MFMA (compiler counted-lgkm), ONE vmcnt(0)+barrier per tile.
// LDS 112 KB: 2 slots x (A 256x64 + B 192x64) fp16, XOR-8 chunk swizzle via
// per-lane pre-swizzled global source (A_h/WqkvT plain; conflicts = 0,
// verified r2-r5). 8 waves: wm=(w>>2)*128, wn=(w&3)*48; acc[8][3];
// 48 MFMA/tile/wave. Epilogue scatter formats unchanged (verified).
// ---------------------------------------------------------------------------
__global__ __launch_bounds__(512, 1) void qkv_gemm8(
    const _Float16* __restrict__ A, const _Float16* __restrict__ Bt,
    const float* __restrict__ bias, _Float16* __restrict__ base)
{
    __shared__ _Float16 SA[2][16384];   // 256 rows x 64
    __shared__ _Float16 SB[2][12288];   // 192 rows x 64
    const int tid = threadIdx.x;
    const int w = tid >> 6, l = tid & 63;
    const int a = l & 15, q4 = l >> 4, a7 = a & 7;
    // 256 blocks -> 8 XCDs x 32; each XCD a 4(bx) x 8(by) rectangle
    const int xc = blockIdx.x & 7, loc = blockIdx.x >> 3;
    const int bx = (xc & 3) * 4 + (loc & 3);
    const int by = (xc >> 2) * 8 + (loc >> 2);
    const int m0 = by * 256, n0 = bx * 192;
    const int wm = (w >> 2) * 128, wn = (w & 3) * 48;

    // stored chunk (tid&7) of row (tid>>3)+64u holds logical chunk
    // (tid&7)^(row&7) -> pre-swizzled per-lane global source
    const int csw = (((tid & 7) ^ ((tid >> 3) & 7)) << 3);
    const _Float16* gA0 = A  + (size_t)(m0 + (tid >> 3)) * 1024 + csw;
    const _Float16* gB0 = Bt + (size_t)(n0 + (tid >> 3)) * 1024 + csw;

    auto stage = [&](int kt, int sl) {
        const size_t ko = (size_t)kt * 64;
#pragma unroll
        for (int u = 0; u < 4; ++u)
            GLDS16(gA0 + (size_t)(u * 64) * 1024 + ko, &SA[sl][0] + u * 4096 + tid * 8);
#pragma unroll
        for (int u = 0; u < 3; ++u)
            GLDS16(gB0 + (size_t)(u * 64) * 1024 + ko, &SB[sl][0] + u * 4096 + tid * 8);
    };

    // prologue: tiles 0 and 1; retire tile 0's 7 loads only
    stage(0, 0); stage(1, 1);
    asm volatile("s_waitcnt vmcnt(7)" ::: "memory");
    __builtin_amdgcn_sched_barrier(0);
    __builtin_amdgcn_s_barrier();
    __builtin_amdgcn_sched_barrier(0);

    f32x4 acc[8][3];
#pragma unroll
    for (int i = 0; i < 8; ++i)
#pragma unroll
        for (int j = 0; j < 3; ++j) acc[i][j] = (f32x4){0.f, 0.f, 0.f, 0.f};

#define FRG(SP, row_, ks_) \
    (*(const f16x8*)&(SP)[(row_) * 64 + ((((ks_) * 4 + q4) ^ a7) << 3)])

    f16x8 aL[4][2], aH[4][2], bf[3][2];
    {   // preload tile-0 first operands: A-lo + B j0,j1
#pragma unroll
        for (int i = 0; i < 4; ++i) {
            aL[i][0] = FRG(SA[0], wm + i * 16 + a, 0);
            aL[i][1] = FRG(SA[0], wm + i * 16 + a, 1);
        }
#pragma unroll
        for (int j = 0; j < 2; ++j) {
            bf[j][0] = FRG(SB[0], wn + j * 16 + a, 0);
            bf[j][1] = FRG(SB[0], wn + j * 16 + a, 1);
        }
    }

    for (int t = 0; t < 16; ++t) {
        const int sl = t & 1, nsl = sl ^ 1;
        const _Float16* sA = &SA[sl][0];
        const _Float16* sB = &SB[sl][0];

        // stage next tile into the slot freed at the end of t-1
        if (t >= 1 && t <= 14) stage(t + 1, nsl);

        // ---- Q0: (A-lo x B01), operands preloaded
        __builtin_amdgcn_s_setprio(1);
#pragma unroll
        for (int i = 0; i < 4; ++i)
#pragma unroll
            for (int j = 0; j < 2; ++j) {
                acc[i][j] = MFMA16(aL[i][0], bf[j][0], acc[i][j]);
                acc[i][j] = MFMA16(aL[i][1], bf[j][1], acc[i][j]);
            }
        __builtin_amdgcn_s_setprio(0);

        // ---- read B j2; Q1: (A-lo x B2)
        bf[2][0] = FRG(sB, wn + 32 + a, 0);
        bf[2][1] = FRG(sB, wn + 32 + a, 1);
        __builtin_amdgcn_s_setprio(1);
#pragma unroll
        for (int i = 0; i < 4; ++i) {
            acc[i][2] = MFMA16(aL[i][0], bf[2][0], acc[i][2]);
            acc[i][2] = MFMA16(aL[i][1], bf[2][1], acc[i][2]);
        }
        __builtin_amdgcn_s_setprio(0);

        // ---- read A-hi; Q2: (A-hi x all B)
#pragma unroll
        for (int i = 0; i < 4; ++i) {
            aH[i][0] = FRG(sA, wm + 64 + i * 16 + a, 0);
            aH[i][1] = FRG(sA, wm + 64 + i * 16 + a, 1);
        }
        __builtin_amdgcn_s_setprio(1);
#pragma unroll
        for (int i = 0; i < 4; ++i)
#pragma unroll
            for (int j = 0; j < 3; ++j) {
                acc[i + 4][j] = MFMA16(aH[i][0], bf[j][0], acc[i + 4][j]);
                acc[i + 4][j] = MFMA16(aH[i][1], bf[j][1], acc[i + 4][j]);
            }
        __builtin_amdgcn_s_setprio(0);

        // ---- tile boundary: drain staging (issued a full tile ago), sync,
        //      preload next tile's first operands
        if (t < 15) {
            asm volatile("s_waitcnt vmcnt(0)" ::: "memory");
            __builtin_amdgcn_sched_barrier(0);
            __builtin_amdgcn_s_barrier();
            __builtin_amdgcn_sched_barrier(0);
            const _Float16* nA = &SA[nsl][0];
            const _Float16* nB = &SB[nsl][0];
#pragma unroll
            for (int i = 0; i < 4; ++i) {
                aL[i][0] = FRG(nA, wm + i * 16 + a, 0);
                aL[i][1] = FRG(nA, wm + i * 16 + a, 1);
            }
#pragma unroll
            for (int j = 0; j < 2; ++j) {
                bf[j][0] = FRG(nB, wn + j * 16 + a, 0);
                bf[j][1] = FRG(nB, wn + j * 16 + a, 1);
            }
        }
    }
#undef FRG

    // ---- epilogue: scatter to q (plain) / k (row-swizzled) / vT (fused
    //      transpose, chunk-swizzled) — formats identical to previous rounds
#pragma unroll
    for (int j = 0; j < 3; ++j) {
        const int n = n0 + wn + 16 * j + a;
        const float bv = bias[n];
        const int tq = n >> 10, h = (n >> 6) & 15, d = n & 63;
#pragma unroll
        for (int i = 0; i < 8; ++i) {
            const int mb = m0 + wm + 16 * i + q4 * 4;
            const int bb = mb >> 11, sb = mb & 2047;
            if (tq == 2) {
                f16x4 ov;
#pragma unroll
                for (int r = 0; r < 4; ++r) ov[r] = (_Float16)(acc[i][j][r] + bv);
                const size_t off =
                    ((size_t)((bb * 16 + h) * 64 + d)) * 2048
                    + (sb & ~63)
                    + ((((sb >> 3) & 7) ^ (d & 7)) << 3) + (sb & 7);
                *(f16x4*)(base + 3 * HBUF + off) = ov;
            } else if (tq == 1) {
#pragma unroll
                for (int r = 0; r < 4; ++r) {
                    const int s = sb + r;
                    const _Float16 val = (_Float16)(acc[i][j][r] + bv);
                    const int dk = ((((d >> 3) ^ (s & 7)) & 7) << 3) | (d & 7);
                    base[HBUF + ((size_t)(bb * 16 + h) * 2048 + s) * 64 + dk] = val;
                }
            } else {
#pragma unroll
                for (int r = 0; r < 4; ++r) {
                    const _Float16 val = (_Float16)(acc[i][j][r] + bv);
                    base[((size_t)(bb * 16 + h) * 2048 + sb + r) * 64 + d] = val;
                }
            }
        }
    }
}

// ---------------------------------------------------------------------------
// MFMA fp16 GEMM, TMx128xBK32, swizzled LDS (conflict-free b128 reads).
// Used only as EPI=1 (dense projection): plain fp32 [M][N] store.
// ---------------------------------------------------------------------------
template<int EPI, int TM>
__global__ __launch_bounds__(256) void mfma_gemm(
    const _Float16* __restrict__ A, const _Float16* __restrict__ Bt,
    const float* __restrict__ bias, void* __restrict__ Cout,
    int M, int N, int K)
{
    __shared__ _Float16 As[TM * 32];
    __shared__ _Float16 Bs[128 * 32];
    constexpr int TI = TM / 32;
    constexpr int AR = TM / 4;

    const int tid = threadIdx.x;
    const int w = tid >> 6, l = tid & 63;
    const int a = l & 15, q4 = l >> 4;
    const int m0 = blockIdx.y * TM, n0 = blockIdx.x * 128;
    const int wm = (w >> 1) * (TM / 2), wn = (w & 1) * 64;

    f32x4 acc[TI][4];
#pragma unroll
    for (int i = 0; i < TI; ++i)
#pragma unroll
        for (int j = 0; j < 4; ++j) acc[i][j] = (f32x4){0.f, 0.f, 0.f, 0.f};

    const _Float16* gA = A + (size_t)(m0 + w * AR + (l >> 2)) * K + (l & 3) * 8;
    const _Float16* gB = Bt + (size_t)(n0 + w * 32 + (l >> 2)) * K + (l & 3) * 8;
    _Float16* sA = As + w * AR * 32;
    _Float16* sB = Bs + w * 1024;

    for (int k0 = 0; k0 < K; k0 += 32) {
#pragma unroll
        for (int u = 0; u < TM / 64; ++u)
            GLDS16(gA + (size_t)u * 16 * K + k0, sA + u * 512);
        GLDS16(gB + k0,          sB);
        GLDS16(gB + 16 * K + k0, sB + 512);
        __syncthreads();

        f16x8 af[TI], bf[4];
        const int pa = (q4 ^ (a & 3)) << 3;
#pragma unroll
        for (int i = 0; i < TI; ++i)
            af[i] = *(const f16x8*)&As[(wm + 16 * i + a) * 32 + pa];
#pragma unroll
        for (int j = 0; j < 4; ++j)
            bf[j] = *(const f16x8*)&Bs[(wn + 16 * j + a) * 32 + pa];
#pragma unroll
        for (int i = 0; i < TI; ++i)
#pragma unroll
            for (int j = 0; j < 4; ++j)
                acc[i][j] = MFMA16(af[i], bf[j], acc[i][j]);
        __syncthreads();
    }

    {
        float* C = (float*)Cout;
#pragma unroll
        for (int j = 0; j < 4; ++j) {
            const int n = n0 + wn + 16 * j + a;
            const float bv = bias[n];
#pragma unroll
            for (int i = 0; i < TI; ++i)
#pragma unroll
                for (int r = 0; r < 4; ++r) {
                    const int m = m0 + wm + 16 * i + q4 * 4 + r;
                    C[(size_t)m * N + n] = acc[i][j][r] + bv;
                }
        }
    }
}

// ---------------------------------------------------------------------------
// Paired-tile flash attention, no-max softmax, 1 barrier/tile.
// (unchanged except setprio(1) around MFMA clusters — m191: +4-7% on attn)
// ---------------------------------------------------------------------------
__global__ __launch_bounds__(256, 2) void attn_mfma(
    const _Float16* __restrict__ qb, const _Float16* __restrict__ kb,
    const _Float16* __restrict__ vtb, _Float16* __restrict__ ctx)
{
    __shared__ _Float16 Ks[2][64 * 64];
    __shared__ _Float16 VT[2][64 * 64];
    __shared__ _Float16 Ps[4][16 * 64];

    const int bid = blockIdx.x;
    const int jj = bid >> 3;
    const int bhIdx = (bid & 7) * 4 + (jj >> 4);   // 0..31
    const int p = jj & 15;
    const int b = bhIdx >> 4, h = bhIdx & 15;
    const int tid = threadIdx.x;
    const int w = tid >> 6, l = tid & 63;
    const int a = l & 15, q4 = l >> 4, a7 = a & 7;
    const size_t bh  = ((size_t)b * NHEAD + h) * SEQ;
    const size_t bhd = ((size_t)b * NHEAD + h) * 64;

    const int qHi = (31 - p) * 64 + w * 16;
    const int qLo = p * 64 + w * 16;
    const int ntiles = 32 - p;

    f16x8 qfh[2], qfl[2];
    {
        const _Float16* qp = qb + (bh + qHi + a) * 64;
        qfh[0] = *(const f16x8*)(qp + q4 * 8);
        qfh[1] = *(const f16x8*)(qp + 32 + q4 * 8);
        const _Float16* ql = qb + (bh + qLo + a) * 64;
        qfl[0] = *(const f16x8*)(ql + q4 * 8);
        qfl[1] = *(const f16x8*)(ql + 32 + q4 * 8);
    }

    f32x4 Oh[4], Ol[4];
#pragma unroll
    for (int c = 0; c < 4; ++c) {
        Oh[c] = (f32x4){0.f, 0.f, 0.f, 0.f};
        Ol[c] = (f32x4){0.f, 0.f, 0.f, 0.f};
    }
    float lh = 0.f, ll = 0.f;

    const _Float16* kg = kb + (bh + w * 16) * 64 + l * 8;
    const int vrow = w * 16 + (l >> 3);
    const _Float16* vg = vtb + (bhd + vrow) * 2048 + (l & 7) * 8;
    _Float16* pbuf = &Ps[w][0];
    const int p0 = (q4 ^ a7) << 3;

    auto stage = [&](int t, int buf) {
        _Float16* ksl = &Ks[buf][0] + w * 1024 + l * 8;
        const _Float16* kt = kg + (size_t)t * 4096;
        GLDS16(kt,       ksl);
        GLDS16(kt + 512, ksl + 512);
        _Float16* vtl = &VT[buf][0] + vrow * 64 + (l & 7) * 8;
        GLDS16(vg + t * 64,            vtl);
        GLDS16(vg + t * 64 + 8 * 2048, vtl + 512);
    };

    stage(0, 0);

    for (int t = 0; t < ntiles; ++t) {
        __syncthreads();                 // tile t landed; prev-iter LDS reads drained
        if (t + 1 < ntiles) stage(t + 1, (t + 1) & 1);

        const _Float16* ksb  = &Ks[t & 1][0];
        const _Float16* vbuf = &VT[t & 1][0];
        const int kt0 = t * 64;
        const bool doLo = (t <= p);

        f32x4 sh[4], sl[4];
        __builtin_amdgcn_s_setprio(1);
#pragma unroll
        for (int n0 = 0; n0 < 4; ++n0) {
            f16x8 kf0 = *(const f16x8*)&ksb[(n0 * 16 + a) * 64 + p0];
            f16x8 kf1 = *(const f16x8*)&ksb[(n0 * 16 + a) * 64 + (p0 ^ 32)];
            f32x4 c = (f32x4){0.f, 0.f, 0.f, 0.f};
            c = MFMA16(kf0, qfh[0], c);
            c = MFMA16(kf1, qfh[1], c);
            sh[n0] = c;
            if (doLo) {
                f32x4 d = (f32x4){0.f, 0.f, 0.f, 0.f};
                d = MFMA16(kf0, qfl[0], d);
                d = MFMA16(kf1, qfl[1], d);
                sl[n0] = d;
            }
        }
        __builtin_amdgcn_s_setprio(0);

        auto half_step = [&](f32x4 st[4], float& lrun, f32x4* O,
                             const bool maskT, const int qbase) {
            if (maskT) {
#pragma unroll
                for (int n0 = 0; n0 < 4; ++n0)
#pragma unroll
                    for (int r = 0; r < 4; ++r) {
                        const int kgl = kt0 + n0 * 16 + q4 * 4 + r;
                        st[n0][r] = (kgl > qbase + a) ? MASK2
                                                      : fmaf(st[n0][r], SCALE2, BIAS2);
                    }
            } else {
#pragma unroll
                for (int n0 = 0; n0 < 4; ++n0)
#pragma unroll
                    for (int r = 0; r < 4; ++r)
                        st[n0][r] = fmaf(st[n0][r], SCALE2, BIAS2);
            }
            float ls = 0.f;
#pragma unroll
            for (int n0 = 0; n0 < 4; ++n0)
#pragma unroll
                for (int r = 0; r < 4; ++r) {
                    const float pe = EXP2F(st[n0][r]);
                    st[n0][r] = pe;
                    ls += pe;
                }
            lrun += ls;
            // P write: keys 16n0+4q4..+3 consecutive -> one b64 per n0
#pragma unroll
            for (int n0 = 0; n0 < 4; ++n0) {
                f16x4 pk;
#pragma unroll
                for (int r = 0; r < 4; ++r) pk[r] = (_Float16)st[n0][r];
                const int pos = (2 * n0 + (q4 >> 1)) ^ a7;
                *(f16x4*)&pbuf[a * 64 + pos * 8 + ((q4 & 1) << 2)] = pk;
            }
            f16x8 pf0 = *(const f16x8*)&pbuf[a * 64 + p0];
            f16x8 pf1 = *(const f16x8*)&pbuf[a * 64 + (p0 ^ 32)];
            __builtin_amdgcn_s_setprio(1);
#pragma unroll
            for (int c = 0; c < 4; ++c) {
                f16x8 vf0 = *(const f16x8*)&vbuf[(c * 16 + a) * 64 + p0];
                f16x8 vf1 = *(const f16x8*)&vbuf[(c * 16 + a) * 64 + (p0 ^ 32)];
                O[c] = MFMA16(vf0, pf0, O[c]);
                O[c] = MFMA16(vf1, pf1, O[c]);
            }
            __builtin_amdgcn_s_setprio(0);
        };

        half_step(sh, lh, Oh, t == 31 - p, qHi);
        if (doLo) half_step(sl, ll, Ol, t == p, qLo);
    }

    // ---- epilogue: reduce l, normalize, store ctx fp16 with GEMM-A swizzle
    auto finish = [&](float lrun, const f32x4* O, const int qbase) {
        float lt = lrun;
        lt += __shfl_xor(lt, 16);
        lt += __shfl_xor(lt, 32);
        const float inv = 1.0f / lt;
        const size_t row = (size_t)b * SEQ + qbase + a;
#pragma unroll
        for (int c = 0; c < 4; ++c) {
            const int d0 = c * 16 + q4 * 4;
            const int kcol = h * 64 + (d0 & ~31)
                           + ((((d0 >> 3) & 3) ^ (a & 3)) << 3) + (d0 & 7);
            f16x4 ov;
#pragma unroll
            for (int r = 0; r < 4; ++r) ov[r] = (_Float16)(O[c][r] * inv);
            *(f16x4*)(ctx + row * HID + kcol) = ov;
        }
    };
    finish(lh, Oh, qHi);
    finish(ll, Ol, qLo);
}

// ---------------------------------------------------------------------------
// WS: [A_h][WqkvT][WdT][q|k(sw)|v(unused)|vT(sw)][ctx]  (all fp16)
// ---------------------------------------------------------------------------
extern "C" void kernel_launch(void* const* d_in, const int* in_sizes, int n_in,
                              void* d_out, int out_size, void* d_ws, size_t ws_size,
                              hipStream_t stream) {
    const float* hs   = (const float*)d_in[0];
    const float* Wqkv = (const float*)d_in[2];
    const float* bqkv = (const float*)d_in[3];
    const float* Wd   = (const float*)d_in[4];
    const float* bd   = (const float*)d_in[5];

    _Float16* A_h   = (_Float16*)d_ws;
    _Float16* WqkvT = A_h + (size_t)MTOT * HID;
    _Float16* WdT   = WqkvT + (size_t)QKVN * HID;
    _Float16* qbuf  = WdT + (size_t)HID * HID;            // q | k(sw) | (v) | vT(sw)
    _Float16* ctxb  = qbuf + 4 * HBUF;

    prep_kernel<<<6144, 256, 0, stream>>>(hs, Wqkv, Wd, A_h, WqkvT, WdT);

    qkv_gemm8<<<256, 512, 0, stream>>>(A_h, WqkvT, bqkv, qbuf);

    attn_mfma<<<512, 256, 0, stream>>>(
        qbuf, qbuf + HBUF, qbuf + 3 * HBUF, ctxb);

    mfma_gemm<1, 64><<<dim3(HID / 128, MTOT / 64), 256, 0, stream>>>(
        ctxb, WdT, bd, d_out, MTOT, HID, HID);
}